// Round 6
// baseline (389.168 us; speedup 1.0000x reference)
//
#include <hip/hip_runtime.h>

typedef __attribute__((ext_vector_type(4))) float f32x4;
typedef __attribute__((ext_vector_type(8))) short s16x8;

#define ADJ_N 8192

__device__ __forceinline__ unsigned short f2bf(float f) {
  unsigned u = __float_as_uint(f);
  u += 0x7FFFu + ((u >> 16) & 1u);
  return (unsigned short)(u >> 16);
}

// ---------------------------------------------------------------------------
// build_B0_plus: B0 = W0 bf16 MFMA fragments [ks][cg][lane][8].
// Blocks >=1016 additionally build W1c fragments; block 0 zeroes frep.
// ---------------------------------------------------------------------------
__global__ __launch_bounds__(256) void build_B0_plus(
    const float* __restrict__ w0, const float* __restrict__ c0,
    const float* __restrict__ w1, const float* __restrict__ c1,
    unsigned short* __restrict__ B0, unsigned short* __restrict__ W1c,
    float* __restrict__ frep) {
  const int bx = blockIdx.x, tid = threadIdx.x;
  {
    const int t = bx * 256 + tid;   // 0..262143
    const int ks = t >> 9;
    const int cg = (t >> 6) & 7;
    const int lane = t & 63;
    const int kb = ks * 32 + ((lane >> 4) << 3);
    const int col = cg * 16 + (lane & 15);
    const int r = kb >> 13;
    const int m = kb & (ADJ_N - 1);
    const float a0 = c0[r * 2 + 0], a1 = c0[r * 2 + 1];
    union { unsigned short v[8]; s16x8 s; } out;
#pragma unroll
    for (int j = 0; j < 8; ++j) {
      const size_t idx = (size_t)(m + j) * 128 + col;
      out.v[j] = f2bf(a0 * w0[idx] + a1 * w0[(size_t)1048576 + idx]);
    }
    ((s16x8*)B0)[t] = out.s;
  }
  if (bx == 0 && tid < 192) frep[tid] = 0.f;
  if (bx >= 1016) {
    const int t2 = (bx - 1016) * 256 + tid;   // 0..2047
    const int f = t2 >> 6;
    const int lane = t2 & 63;
    const int r = f >> 4;
    const int ks2 = (f >> 2) & 3;
    const int cg = f & 3;
    const float a0 = c1[r * 2 + 0], a1 = c1[r * 2 + 1];
    union { unsigned short v[8]; s16x8 s; } out;
#pragma unroll
    for (int j = 0; j < 8; ++j) {
      const int o = ks2 * 32 + ((lane >> 4) << 3) + j;
      const int p = cg * 16 + (lane & 15);
      out.v[j] = f2bf(a0 * w1[(size_t)o * 64 + p] + a1 * w1[8192 + (size_t)o * 64 + p]);
    }
    ((s16x8*)W1c)[t2] = out.s;
  }
}

// ---------------------------------------------------------------------------
// gemm1: partial0[split][n][c] = sum_{k in split} adj[n][k] * W0frag[k][c]
// EXACT r4 body (proven r2/r3/r4): BM=64, 4 waves, wave-private A
// (global->reg->cvt), B double-buffered in LDS via global_load_lds.
// ---------------------------------------------------------------------------
__global__ __launch_bounds__(256, 4) void gemm1_adj(
    const float* __restrict__ adj, const unsigned short* __restrict__ Bfr,
    float* __restrict__ outp) {
  constexpr int BN = 128, CGS = 8, BK = 64, NSTEP = 32;
  __shared__ __align__(16) unsigned short Bsb[2][2 * CGS * 512];  // 32 KB

  const int bx = blockIdx.x;
  const int mblk = bx >> 3;
  const int split = bx & 7;
  const int n0 = mblk * 64;
  const int k0 = split * 2048;
  const int r = k0 >> 13;
  const int m0k = k0 & (ADJ_N - 1);

  const int tid = threadIdx.x;
  const int w = tid >> 6;
  const int lane = tid & 63;
  const int lhi = lane >> 4, llo = lane & 15;
  const int rowa = n0 + w * 16 + llo;

  const float* __restrict__ adjw =
      adj + ((size_t)r << 26) + (size_t)rowa * ADJ_N + m0k + lhi * 8;

  f32x4 acc[CGS];
#pragma unroll
  for (int b = 0; b < CGS; ++b) acc[b] = (f32x4){0.f, 0.f, 0.f, 0.f};

  auto loadA = [&](int step, f32x4 (&dst)[4]) {
#pragma unroll
    for (int kc = 0; kc < 2; ++kc)
#pragma unroll
      for (int h = 0; h < 2; ++h)
        dst[kc * 2 + h] = *(const f32x4*)(adjw + step * BK + kc * 32 + h * 4);
  };

  auto stageB = [&](int buf, int step) {
    const int ksb = (k0 >> 5) + step * 2;
    const unsigned short* g = Bfr + (size_t)ksb * CGS * 512 + w * (CGS / 2) * 512 + lane * 8;
#pragma unroll
    for (int i = 0; i < CGS / 2; ++i) {
      __builtin_amdgcn_global_load_lds(
          (const __attribute__((address_space(1))) void*)(g + i * 512),
          (__attribute__((address_space(3))) void*)((char*)&Bsb[buf][0] +
                                                    (w * (CGS / 2) + i) * 1024),
          16, 0, 0);
    }
  };

  auto compute = [&](int buf, f32x4 (&cur)[4]) {
#pragma unroll
    for (int kc = 0; kc < 2; ++kc) {
      union { unsigned u[4]; s16x8 v; } cv;
      asm("v_cvt_pk_bf16_f32 %0, %1, %2" : "=v"(cv.u[0]) : "v"(cur[kc * 2][0]), "v"(cur[kc * 2][1]));
      asm("v_cvt_pk_bf16_f32 %0, %1, %2" : "=v"(cv.u[1]) : "v"(cur[kc * 2][2]), "v"(cur[kc * 2][3]));
      asm("v_cvt_pk_bf16_f32 %0, %1, %2" : "=v"(cv.u[2]) : "v"(cur[kc * 2 + 1][0]), "v"(cur[kc * 2 + 1][1]));
      asm("v_cvt_pk_bf16_f32 %0, %1, %2" : "=v"(cv.u[3]) : "v"(cur[kc * 2 + 1][2]), "v"(cur[kc * 2 + 1][3]));
#pragma unroll
      for (int fc = 0; fc < CGS; ++fc) {
        const s16x8 b = *(const s16x8*)((const char*)&Bsb[buf][0] +
                                        (((kc * CGS + fc) * 64 + lane) << 4));
        acc[fc] = __builtin_amdgcn_mfma_f32_16x16x32_bf16(cv.v, b, acc[fc], 0, 0, 0);
      }
    }
  };

  f32x4 a0[4], a1[4];
  loadA(0, a0);
  stageB(0, 0);
  __syncthreads();

  for (int s2 = 0; s2 < NSTEP; s2 += 2) {
    stageB(1, s2 + 1);
    loadA(s2 + 1, a1);
    compute(0, a0);
    __syncthreads();
    if (s2 + 2 < NSTEP) {
      stageB(0, s2 + 2);
      loadA(s2 + 2, a0);
    }
    compute(1, a1);
    __syncthreads();
  }

  float* po = outp + ((size_t)split * ADJ_N + (size_t)n0) * BN;
#pragma unroll
  for (int fc = 0; fc < CGS; ++fc)
#pragma unroll
    for (int q = 0; q < 4; ++q)
      po[(size_t)(w * 16 + lhi * 4 + q) * BN + fc * 16 + llo] = acc[fc][q];
}

// ---------------------------------------------------------------------------
// gemm2: partial1[split][n][c] = sum_{k in split} adj[n][k] * B1frag[k][c]
// EXACT r4 body: REV K-walk (L3 reuse of gemm1's co-resident tail).
// ---------------------------------------------------------------------------
__global__ __launch_bounds__(256, 4) void gemm2_adj(
    const float* __restrict__ adj, const unsigned short* __restrict__ Bfr,
    float* __restrict__ outp) {
  constexpr int BN = 64, CGS = 4, BK = 64, NSTEP = 32;
  __shared__ __align__(16) unsigned short Bsb[2][2 * CGS * 512];  // 16 KB

  const int bx = blockIdx.x;
  const int mblk = bx >> 3;
  const int split = bx & 7;
  const int n0 = mblk * 64;
  const int k0 = split * 2048;
  const int r = k0 >> 13;
  const int m0k = k0 & (ADJ_N - 1);

  const int tid = threadIdx.x;
  const int w = tid >> 6;
  const int lane = tid & 63;
  const int lhi = lane >> 4, llo = lane & 15;
  const int rowa = n0 + w * 16 + llo;

  const float* __restrict__ adjw =
      adj + ((size_t)r << 26) + (size_t)rowa * ADJ_N + m0k + lhi * 8;

  f32x4 acc[CGS];
#pragma unroll
  for (int b = 0; b < CGS; ++b) acc[b] = (f32x4){0.f, 0.f, 0.f, 0.f};

  auto loadA = [&](int step, f32x4 (&dst)[4]) {
#pragma unroll
    for (int kc = 0; kc < 2; ++kc)
#pragma unroll
      for (int h = 0; h < 2; ++h)
        dst[kc * 2 + h] = *(const f32x4*)(adjw + step * BK + kc * 32 + h * 4);
  };

  auto stageB = [&](int buf, int step) {
    const int ksb = (k0 >> 5) + step * 2;
    const unsigned short* g = Bfr + (size_t)ksb * CGS * 512 + w * (CGS / 2) * 512 + lane * 8;
#pragma unroll
    for (int i = 0; i < CGS / 2; ++i) {
      __builtin_amdgcn_global_load_lds(
          (const __attribute__((address_space(1))) void*)(g + i * 512),
          (__attribute__((address_space(3))) void*)((char*)&Bsb[buf][0] +
                                                    (w * (CGS / 2) + i) * 1024),
          16, 0, 0);
    }
  };

  auto compute = [&](int buf, f32x4 (&cur)[4]) {
#pragma unroll
    for (int kc = 0; kc < 2; ++kc) {
      union { unsigned u[4]; s16x8 v; } cv;
      asm("v_cvt_pk_bf16_f32 %0, %1, %2" : "=v"(cv.u[0]) : "v"(cur[kc * 2][0]), "v"(cur[kc * 2][1]));
      asm("v_cvt_pk_bf16_f32 %0, %1, %2" : "=v"(cv.u[1]) : "v"(cur[kc * 2][2]), "v"(cur[kc * 2][3]));
      asm("v_cvt_pk_bf16_f32 %0, %1, %2" : "=v"(cv.u[2]) : "v"(cur[kc * 2 + 1][0]), "v"(cur[kc * 2 + 1][1]));
      asm("v_cvt_pk_bf16_f32 %0, %1, %2" : "=v"(cv.u[3]) : "v"(cur[kc * 2 + 1][2]), "v"(cur[kc * 2 + 1][3]));
#pragma unroll
      for (int fc = 0; fc < CGS; ++fc) {
        const s16x8 b = *(const s16x8*)((const char*)&Bsb[buf][0] +
                                        (((kc * CGS + fc) * 64 + lane) << 4));
        acc[fc] = __builtin_amdgcn_mfma_f32_16x16x32_bf16(cv.v, b, acc[fc], 0, 0, 0);
      }
    }
  };

  f32x4 a0[4], a1[4];
  loadA(NSTEP - 1, a0);
  stageB(0, NSTEP - 1);
  __syncthreads();

  for (int s2 = 0; s2 < NSTEP; s2 += 2) {
    stageB(1, NSTEP - 2 - s2);
    loadA(NSTEP - 2 - s2, a1);
    compute(0, a0);
    __syncthreads();
    if (s2 + 2 < NSTEP) {
      stageB(0, NSTEP - 3 - s2);
      loadA(NSTEP - 3 - s2, a0);
    }
    compute(1, a1);
    __syncthreads();
  }

  float* po = outp + ((size_t)split * ADJ_N + (size_t)n0) * BN;
#pragma unroll
  for (int fc = 0; fc < CGS; ++fc)
#pragma unroll
    for (int q = 0; q < 4; ++q)
      po[(size_t)(w * 16 + lhi * 4 + q) * BN + fc * 16 + llo] = acc[fc][q];
}

// ---------------------------------------------------------------------------
// reduce_h: h = relu(sum of 8 p0 splits); colsum0 (pre-relu) -> frep[0:128].
// 1024 blocks x 256 threads, 8 rows each, f32x4 lanes.
// ---------------------------------------------------------------------------
__global__ __launch_bounds__(256) void reduce_h(
    const float* __restrict__ p0, float* __restrict__ h,
    float* __restrict__ frep) {
  __shared__ f32x4 red[256];
  const int t = threadIdx.x;
  const int c4 = t & 31, row = t >> 5;
  const size_t idx = ((size_t)blockIdx.x * 8 + row) * 128 + c4 * 4;
  f32x4 s = (f32x4){0.f, 0.f, 0.f, 0.f};
#pragma unroll
  for (int sp = 0; sp < 8; ++sp)
    s += *(const f32x4*)&p0[(size_t)sp * 1048576 + idx];
  f32x4 hv;
#pragma unroll
  for (int j = 0; j < 4; ++j) hv[j] = fmaxf(s[j], 0.f);
  *(f32x4*)&h[idx] = hv;
  red[t] = s;
  __syncthreads();
  if (t < 32) {
    f32x4 a = red[t] + red[t + 32] + red[t + 64] + red[t + 96] +
              red[t + 128] + red[t + 160] + red[t + 192] + red[t + 224];
#pragma unroll
    for (int j = 0; j < 4; ++j) atomicAdd(&frep[t * 4 + j], a[j]);
  }
}

// ---------------------------------------------------------------------------
// build_B1_mfma: Hc[k=r*8192+m][p] = sum_o h[m][o]*W1c[r][o][p] via MFMA,
// scattered to gemm2's B-fragment layout. 512 blocks (r = bx&1) x 128 thr.
// W1c staged via plain reg->LDS (16 KB, zero exotic dependences).
// ---------------------------------------------------------------------------
__global__ __launch_bounds__(128) void build_B1_mfma(
    const float* __restrict__ h, const unsigned short* __restrict__ W1c,
    unsigned short* __restrict__ Bsw1) {
  __shared__ __align__(16) float hs[32][132];
  __shared__ __align__(16) unsigned short wfr[8192];  // 16 KB: this r's frags
  __shared__ __align__(16) float T[2][16 * 68];
  const int tid = threadIdx.x;
  const int r = blockIdx.x & 1;
  const int m0 = (blockIdx.x >> 1) * 32;

  // stage W1c fragments: plain loads -> LDS stores
#pragma unroll
  for (int i = 0; i < 8; ++i) {
    const int slot = i * 128 + tid;  // 0..1023
    ((s16x8*)wfr)[slot] = ((const s16x8*)W1c)[r * 1024 + slot];
  }
  // load h tile 32x128
  const f32x4* hg = (const f32x4*)(h + (size_t)m0 * 128);
#pragma unroll
  for (int i = 0; i < 8; ++i) {
    const int v = i * 128 + tid;
    const f32x4 val = hg[v];
    *(f32x4*)&hs[v >> 5][(v & 31) * 4] = val;
  }
  __syncthreads();

  const int w = tid >> 6;
  const int lane = tid & 63;
  const int hi = lane >> 4, llo = lane & 15;
  const int row = w * 16 + llo;

  f32x4 acc[4];
#pragma unroll
  for (int cg = 0; cg < 4; ++cg) acc[cg] = (f32x4){0.f, 0.f, 0.f, 0.f};

#pragma unroll
  for (int ks2 = 0; ks2 < 4; ++ks2) {
    const f32x4 lo = *(const f32x4*)&hs[row][ks2 * 32 + hi * 8];
    const f32x4 hi4 = *(const f32x4*)&hs[row][ks2 * 32 + hi * 8 + 4];
    union { unsigned u[4]; s16x8 v; } cv;
    asm("v_cvt_pk_bf16_f32 %0, %1, %2" : "=v"(cv.u[0]) : "v"(lo[0]), "v"(lo[1]));
    asm("v_cvt_pk_bf16_f32 %0, %1, %2" : "=v"(cv.u[1]) : "v"(lo[2]), "v"(lo[3]));
    asm("v_cvt_pk_bf16_f32 %0, %1, %2" : "=v"(cv.u[2]) : "v"(hi4[0]), "v"(hi4[1]));
    asm("v_cvt_pk_bf16_f32 %0, %1, %2" : "=v"(cv.u[3]) : "v"(hi4[2]), "v"(hi4[3]));
#pragma unroll
    for (int cg = 0; cg < 4; ++cg) {
      const s16x8 b = *(const s16x8*)&wfr[((ks2 * 4 + cg) * 64 + lane) * 8];
      acc[cg] = __builtin_amdgcn_mfma_f32_16x16x32_bf16(cv.v, b, acc[cg], 0, 0, 0);
    }
  }

  float* Tw = &T[w][0];
#pragma unroll
  for (int cg = 0; cg < 4; ++cg)
#pragma unroll
    for (int q = 0; q < 4; ++q)
      Tw[(hi * 4 + q) * 68 + cg * 16 + llo] = acc[cg][q];
  __builtin_amdgcn_s_waitcnt(0);
  if ((hi >> 1) == w) {
    const int mloc0 = 8 * hi - w * 16;
    const int ks = (r * ADJ_N + m0) >> 5;
#pragma unroll
    for (int cg = 0; cg < 4; ++cg) {
      union { unsigned u[4]; s16x8 v; } pk;
#pragma unroll
      for (int jj = 0; jj < 4; ++jj) {
        const float f0 = Tw[(mloc0 + 2 * jj) * 68 + cg * 16 + llo];
        const float f1 = Tw[(mloc0 + 2 * jj + 1) * 68 + cg * 16 + llo];
        asm("v_cvt_pk_bf16_f32 %0, %1, %2" : "=v"(pk.u[jj]) : "v"(f0), "v"(f1));
      }
      *(s16x8*)&Bsw1[((size_t)(ks * 4 + cg) * 64 + lane) * 8] = pk.v;
    }
  }
}

// ---------------------------------------------------------------------------
// reduce_out1: out1 = sum of 8 partials; colsum -> frep[128:192].
// 512 blocks x 256 threads, 16 rows each, f32x4 lanes.
// ---------------------------------------------------------------------------
__global__ __launch_bounds__(256) void reduce_out1(
    const float* __restrict__ p1, float* __restrict__ out1,
    float* __restrict__ frep) {
  __shared__ f32x4 red[256];
  const int t = threadIdx.x;
  const int c4 = t & 15, row = t >> 4;
  const size_t idx = ((size_t)blockIdx.x * 16 + row) * 64 + c4 * 4;
  f32x4 s = (f32x4){0.f, 0.f, 0.f, 0.f};
#pragma unroll
  for (int sp = 0; sp < 8; ++sp)
    s += *(const f32x4*)&p1[(size_t)sp * 524288 + idx];
  *(f32x4*)&out1[idx] = s;
  red[t] = s;
  __syncthreads();
  if (t < 16) {
    f32x4 a = (f32x4){0.f, 0.f, 0.f, 0.f};
#pragma unroll
    for (int g = 0; g < 16; ++g) a += red[t + g * 16];
#pragma unroll
    for (int j = 0; j < 4; ++j) atomicAdd(&frep[128 + t * 4 + j], a[j]);
  }
}

// ---------------------------------------------------------------------------
extern "C" void kernel_launch(void* const* d_in, const int* in_sizes, int n_in,
                              void* d_out, int out_size, void* d_ws, size_t ws_size,
                              hipStream_t stream) {
  const float* adj = (const float*)d_in[0];
  const float* bw0 = (const float*)d_in[1];
  const float* bc0 = (const float*)d_in[2];
  const float* bw1 = (const float*)d_in[3];
  const float* bc1 = (const float*)d_in[4];
  float* out = (float*)d_out;
  float* frep = out + (size_t)8192 * 64;

  char* ws = (char*)d_ws;
  float* p0 = (float*)ws;                                      // 32 MB
  float* p1 = (float*)(ws + (32u << 20));                      // 16 MB
  unsigned short* B0 = (unsigned short*)(ws + (48u << 20));    // 4 MB
  unsigned short* B1 = (unsigned short*)(ws + (52u << 20));    // 2 MB
  float* h = (float*)(ws + (56u << 20));                       // 4 MB
  unsigned short* W1c = (unsigned short*)(ws + (60u << 20));   // 32 KB

  build_B0_plus<<<1024, 256, 0, stream>>>(bw0, bc0, bw1, bc1, B0, W1c, frep);
  gemm1_adj<<<1024, 256, 0, stream>>>(adj, B0, p0);
  reduce_h<<<1024, 256, 0, stream>>>(p0, h, frep);
  build_B1_mfma<<<512, 128, 0, stream>>>(h, W1c, B1);
  gemm2_adj<<<1024, 256, 0, stream>>>(adj, B1, p1);
  reduce_out1<<<512, 256, 0, stream>>>(p1, out, frep);
}